// Round 1
// baseline (2498.285 us; speedup 1.0000x reference)
//
#include <hip/hip_runtime.h>
#include <math.h>

#define NSPEC 18424

static constexpr int OFF[25] = {0,1,10,35,84,165,286,455,680,969,1330,1771,2300,2925,
                                3654,4495,5456,6545,7770,9139,10660,12341,14190,16215,18424};
static constexpr double PI_D = 3.14159265358979323846264338327950288;
static constexpr float SCALING_F = 0.07216878364870322f; // 1/sqrt(12*16)

__device__ __forceinline__ void cfma(float2& acc, float2 a, float2 b){
    acc.x += a.x*b.x - a.y*b.y;
    acc.y += a.x*b.y + a.y*b.x;
}

// ---------------------------------------------------------------------------
// K0: Wigner-d tables on device (fp64). grid (l=24, beta=60), block 64.
//   bi < 48  : quadrature betas -> wig_w (weighted), wig_u (*(2l+1))
//   bi >= 48 : the 12 GRID rotations -> conjD[p][s] = e^{+i m' a} d^l_{m'm}(b)
// ---------------------------------------------------------------------------
__global__ __launch_bounds__(64) void k0_wigner(float* __restrict__ wig_w,
                                                float* __restrict__ wig_u,
                                                float2* __restrict__ conjD){
    const int l = blockIdx.x, bi = blockIdx.y, L = 2*l+1;
    __shared__ double lnf[104];
    const int t = threadIdx.x;
    for (int i = t; i < 104; i += 64){
        double s = 0.0;
        for (int k = 2; k <= i; ++k) s += log((double)k);
        lnf[i] = s;
    }
    __syncthreads();
    double beta, alpha = 0.0, wq = 0.0;
    const bool isq = (bi < 48);
    if (isq){
        beta = (bi + 0.5)*PI_D/48.0;
        double acc = 0.0;
        for (int k = 0; k < 24; ++k)
            acc += sin((double)(2*bi+1)*(double)(2*k+1)*PI_D/96.0)/(double)(2*k+1);
        wq = (2.0/24.0)*sin(PI_D*(double)(2*bi+1)/96.0)*acc*0.5;
    } else {
        int p = bi - 48;
        alpha = (double)(p >> 1)*(PI_D/3.0);
        beta  = (p & 1) ? PI_D/8.0 : PI_D/16.0;
    }
    const double ch = cos(0.5*beta), sh = sin(0.5*beta);
    const double lc = log(ch), ls = log(sh);
    for (int r = t; r < L; r += 64){
        const int mp = r - l;
        for (int c = 0; c < L; ++c){
            const int mm = c - l;
            const int k0 = max(0, mm - mp), k1 = min(l + mm, l - mp);
            const double pre = 0.5*(lnf[l+mp] + lnf[l-mp] + lnf[l+mm] + lnf[l-mm]);
            double d = 0.0;
            for (int k = k0; k <= k1; ++k){
                const int ec = 2*l - 2*k + mm - mp, es = 2*k + mp - mm;
                const double term = exp(pre - lnf[l+mm-k] - lnf[k] - lnf[mp-mm+k]
                                        - lnf[l-mp-k] + (double)ec*lc + (double)es*ls);
                d += ((mp - mm + k) & 1) ? -term : term;
            }
            if (isq){
                const int idx = 48*OFF[l] + (bi*L + r)*L + c;
                wig_w[idx] = (float)(wq*d);
                wig_u[idx] = (float)((double)(2*l+1)*d);
            } else {
                const int p = bi - 48;
                conjD[(size_t)p*NSPEC + OFF[l] + r*L + c] =
                    make_float2((float)(cos((double)mp*alpha)*d),
                                (float)(sin((double)mp*alpha)*d));
            }
        }
    }
}

// K0b: twiddle tables (fp64 -> fp32). 1 block, 256 threads.
__global__ __launch_bounds__(256) void k_twiddles(float2* __restrict__ tw1a,
                                                  float2* __restrict__ tw1b,
                                                  float2* __restrict__ twI1,
                                                  float2* __restrict__ twI2){
    const int t = threadIdx.x;
    for (int i = t; i < 24*48; i += 256){
        int m = i/48, a = i%48;
        double th = 2.0*PI_D*(double)(m*a)/48.0;
        tw1a[i] = make_float2((float)cos(th), (float)(-sin(th)));
        twI2[i] = make_float2((float)cos(th), (float)sin(th));
    }
    for (int i = t; i < 48*48; i += 256){
        int n = i/48, c = i%48;
        double th = 2.0*PI_D*(double)(n*c)/48.0;
        tw1b[i] = make_float2((float)cos(th), (float)(-sin(th)));
    }
    for (int i = t; i < 47*48; i += 256){
        int nn = i/48, c = i%48;
        double th = 2.0*PI_D*(double)((nn-23)*c)/48.0;
        twI1[i] = make_float2((float)cos(th), (float)sin(th));
    }
}

// ---------------------------------------------------------------------------
// K1a: DFT over axis a (real->cmplx), m = 0..23 only (Hermitian half).
// A1[j][m][z][c] = sum_a x[z,j,a,c] e^{-i 2pi m a/48}. grid (j=48, z=256), 192 thr.
// ---------------------------------------------------------------------------
__global__ __launch_bounds__(192) void k1a(const float* __restrict__ x,
                                           const float2* __restrict__ tw1a,
                                           float2* __restrict__ A1){
    const int j = blockIdx.x, z = blockIdx.y;
    __shared__ float xs[48*49];
    const float* src = x + (size_t)(z*48 + j)*2304;
    for (int e = threadIdx.x; e < 2304; e += 192)
        xs[(e/48)*49 + (e%48)] = src[e];
    __syncthreads();
    const int c = threadIdx.x % 48, mq = threadIdx.x / 48;
    float ar[6], ai[6];
    #pragma unroll
    for (int i = 0; i < 6; ++i){ ar[i] = 0.f; ai[i] = 0.f; }
    for (int a = 0; a < 48; ++a){
        const float xv = xs[a*49 + c];
        #pragma unroll
        for (int i = 0; i < 6; ++i){
            const float2 tw = tw1a[(mq*6 + i)*48 + a];
            ar[i] += xv*tw.x; ai[i] += xv*tw.y;
        }
    }
    #pragma unroll
    for (int i = 0; i < 6; ++i){
        const int m = mq*6 + i;
        A1[((size_t)(j*24 + m)*256 + z)*48 + c] = make_float2(ar[i], ai[i]);
    }
}

// ---------------------------------------------------------------------------
// K1b: DFT over axis c. Xf[j][m][n][z] = sum_c A1[j][m][z][c] e^{-i 2pi n c/48}
// grid (m=24, j=48, zt=2), 256 thr; thread = (z in 128, n-half).
// ---------------------------------------------------------------------------
__global__ __launch_bounds__(256) void k1b(const float2* __restrict__ A1,
                                           const float2* __restrict__ tw1b,
                                           float2* __restrict__ Xf){
    const int m = blockIdx.x, j = blockIdx.y, zt = blockIdx.z;
    __shared__ float2 as_[48*129];
    const float2* src = A1 + ((size_t)(j*24 + m)*256 + zt*128)*48;
    for (int e = threadIdx.x; e < 6144; e += 256)
        as_[(e%48)*129 + (e/48)] = src[e];
    __syncthreads();
    const int z = threadIdx.x & 127, nh = threadIdx.x >> 7;
    float2 acc[24];
    #pragma unroll
    for (int i = 0; i < 24; ++i) acc[i] = make_float2(0.f, 0.f);
    for (int cc = 0; cc < 48; ++cc){
        const float2 xv = as_[cc*129 + z];
        #pragma unroll
        for (int i = 0; i < 24; ++i)
            cfma(acc[i], xv, tw1b[(nh*24 + i)*48 + cc]);
    }
    #pragma unroll
    for (int i = 0; i < 24; ++i){
        const int n = nh*24 + i;
        Xf[((size_t)(j*24 + m)*48 + n)*256 + zt*128 + z] = acc[i];
    }
}

// ---------------------------------------------------------------------------
// K2: Wigner beta-quadrature -> Fx[s][z]. grid (mf 47, nf 47), 256 thr (z).
// Hermitian: for mf<0, X[mf,nf] = conj(Xstore[-mf, (-nf) mod 48]).
// ---------------------------------------------------------------------------
__global__ __launch_bounds__(256) void k2(const float2* __restrict__ Xf,
                                          const float* __restrict__ wigw,
                                          float2* __restrict__ Fx){
    const int mf = (int)blockIdx.x - 23, nf = (int)blockIdx.y - 23;
    const int z = threadIdx.x;
    const int am = mf < 0 ? -mf : mf;
    const int anf = nf < 0 ? -nf : nf;
    const int lmin = am > anf ? am : anf;
    const int nidx = ((mf < 0 ? -nf : nf) + 48) % 48;
    const float sgn = mf < 0 ? -1.f : 1.f;
    float ar[24], ai[24];
    int widx[24];
    #pragma unroll
    for (int l = 0; l < 24; ++l){
        ar[l] = 0.f; ai[l] = 0.f;
        widx[l] = 48*OFF[l] + (l+mf)*(2*l+1) + (l+nf);
    }
    for (int j = 0; j < 48; ++j){
        const float2 xv = Xf[((size_t)(j*24 + am)*48 + nidx)*256 + z];
        const float xi = sgn*xv.y;
        #pragma unroll
        for (int l = 0; l < 24; ++l){
            if (l >= lmin){
                const float w = wigw[widx[l]];
                ar[l] += w*xv.x; ai[l] += w*xi;
            }
            widx[l] += (2*l+1)*(2*l+1);
        }
    }
    #pragma unroll
    for (int l = 0; l < 24; ++l){
        if (l >= lmin){
            const int L = 2*l+1;
            Fx[((size_t)(OFF[l] + (l+mf)*L + (l+nf)))*256 + z] = make_float2(ar[l], ai[l]);
        }
    }
}

// K3: Fy[s][f*16+g] = SCALING * sum_p kern[f,g,p] * conjD[p][s]
__global__ __launch_bounds__(256) void k3(const float* __restrict__ kern,
                                          const float2* __restrict__ conjD,
                                          float2* __restrict__ Fy){
    const int s = blockIdx.x, t = threadIdx.x;
    float kr[12];
    #pragma unroll
    for (int p = 0; p < 12; ++p) kr[p] = kern[t*12 + p];
    float accr = 0.f, acci = 0.f;
    #pragma unroll
    for (int p = 0; p < 12; ++p){
        const float2 D = conjD[(size_t)p*NSPEC + s];
        accr += kr[p]*D.x; acci += kr[p]*D.y;
    }
    Fy[(size_t)s*256 + t] = make_float2(SCALING_F*accr, SCALING_F*acci);
}

// ---------------------------------------------------------------------------
// K4: so3_mm. block = one (l,mr,nc) spectral row, 64 thr, 2x2 register tile.
// Fz[s][b*16+g] = sum_k sum_f Fx[(mr,k)][b*16+f] * Fy[(k,nc)][f*16+g]
// ---------------------------------------------------------------------------
__global__ __launch_bounds__(64) void k4(const float2* __restrict__ Fx,
                                         const float2* __restrict__ Fy,
                                         float2* __restrict__ Fz){
    const int s = blockIdx.x;
    int l = 0;
    #pragma unroll
    for (int i = 0; i < 24; ++i) if (s >= OFF[i+1]) l = i+1;
    const int L = 2*l+1;
    const int sl = s - OFF[l];
    const int mr = sl / L, nc = sl % L;
    __shared__ float2 xs[16*17];
    __shared__ float2 ys[256];
    const int t = threadIdx.x;
    const int b0 = (t >> 3)*2, g0 = (t & 7)*2;
    float2 a00 = {0,0}, a01 = {0,0}, a10 = {0,0}, a11 = {0,0};
    const float2* xrow = Fx + (size_t)(OFF[l] + mr*L)*256;
    const float2* yrow = Fy + (size_t)(OFF[l] + nc)*256;
    for (int k = 0; k < L; ++k){
        __syncthreads();
        for (int e = t; e < 256; e += 64){
            const float2 xv = xrow[(size_t)k*256 + e];
            xs[(e >> 4)*17 + (e & 15)] = xv;
            ys[e] = yrow[(size_t)k*L*256 + e];
        }
        __syncthreads();
        #pragma unroll
        for (int f = 0; f < 16; ++f){
            const float2 xa = xs[b0*17 + f];
            const float2 xb = xs[(b0+1)*17 + f];
            const float2 ya = ys[f*16 + g0];
            const float2 yb = ys[f*16 + g0 + 1];
            cfma(a00, xa, ya); cfma(a01, xa, yb);
            cfma(a10, xb, ya); cfma(a11, xb, yb);
        }
    }
    float2* dst = Fz + (size_t)s*256;
    dst[b0*16 + g0]       = a00;
    dst[b0*16 + g0 + 1]   = a01;
    dst[(b0+1)*16 + g0]   = a10;
    dst[(b0+1)*16 + g0+1] = a11;
}

// ---------------------------------------------------------------------------
// K5: inverse Wigner -> S[m][nn][j][z] (m = 0..23 Hermitian half, nn = nf+23)
// ---------------------------------------------------------------------------
__global__ __launch_bounds__(256) void k5(const float2* __restrict__ Fz,
                                          const float* __restrict__ wigu,
                                          float2* __restrict__ S){
    const int mf = blockIdx.x;            // 0..23
    const int nf = (int)blockIdx.y - 23;  // -23..23
    const int z = threadIdx.x;
    const int anf = nf < 0 ? -nf : nf;
    const int lmin = mf > anf ? mf : anf;
    float2 fz[24];
    int widx[24];
    #pragma unroll
    for (int l = 0; l < 24; ++l){
        const int L = 2*l+1;
        fz[l] = (l >= lmin) ? Fz[((size_t)(OFF[l] + (l+mf)*L + (l+nf)))*256 + z]
                            : make_float2(0.f, 0.f);
        widx[l] = 48*OFF[l] + (l+mf)*L + (l+nf);
    }
    const int nn = nf + 23;
    for (int j = 0; j < 48; ++j){
        float sr = 0.f, si = 0.f;
        #pragma unroll
        for (int l = 0; l < 24; ++l){
            if (l >= lmin){
                const float w = wigu[widx[l]];
                sr += w*fz[l].x; si += w*fz[l].y;
            }
            widx[l] += (2*l+1)*(2*l+1);
        }
        S[((size_t)(mf*47 + nn)*48 + j)*256 + z] = make_float2(sr, si);
    }
}

// ---------------------------------------------------------------------------
// I1: inverse DFT over n. U[j][z][m][c] = sum_nn S[m][nn][j][z] e^{+i 2pi (nn-23) c/48}
// grid (m=24, j=48, zt=2), 256 thr (z128 x c-half).
// ---------------------------------------------------------------------------
__global__ __launch_bounds__(256) void i1(const float2* __restrict__ S,
                                          const float2* __restrict__ twI1,
                                          float2* __restrict__ U){
    const int m = blockIdx.x, j = blockIdx.y, zt = blockIdx.z;
    __shared__ float2 sl_[47*129];
    for (int e = threadIdx.x; e < 47*128; e += 256){
        const int nn = e >> 7, zl = e & 127;
        sl_[nn*129 + zl] = S[((size_t)(m*47 + nn)*48 + j)*256 + zt*128 + zl];
    }
    __syncthreads();
    const int z = threadIdx.x & 127, ch = threadIdx.x >> 7;
    float2 acc[24];
    #pragma unroll
    for (int i = 0; i < 24; ++i) acc[i] = make_float2(0.f, 0.f);
    for (int nn = 0; nn < 47; ++nn){
        const float2 sv = sl_[nn*129 + z];
        #pragma unroll
        for (int i = 0; i < 24; ++i)
            cfma(acc[i], sv, twI1[nn*48 + ch*24 + i]);
    }
    float2* dst = U + ((size_t)(j*256 + zt*128 + z)*24 + m)*48 + ch*24;
    #pragma unroll
    for (int i = 0; i < 24; ++i) dst[i] = acc[i];
}

// ---------------------------------------------------------------------------
// I2: inverse DFT over m with Hermitian combine -> real out.
// out[z,j,a,c] = (ReU[0,c] + 2*sum_{m=1..23}(cos(wma)ReU[m,c]-sin(wma)ImU[m,c]))/2304
// ---------------------------------------------------------------------------
__global__ __launch_bounds__(256) void i2(const float2* __restrict__ U,
                                          const float2* __restrict__ twI2,
                                          float* __restrict__ out){
    const int z = blockIdx.x, j = blockIdx.y;
    __shared__ float2 uv[24*49];
    const float2* src = U + (size_t)(j*256 + z)*1152;
    for (int e = threadIdx.x; e < 1152; e += 256)
        uv[(e/48)*49 + (e%48)] = src[e];
    __syncthreads();
    float* dst = out + (size_t)(z*48 + j)*2304;
    for (int o = threadIdx.x; o < 2304; o += 256){
        const int a = o / 48, c = o % 48;
        float acc = uv[c].x;  // m = 0 term
        #pragma unroll
        for (int m = 1; m < 24; ++m){
            const float2 tw = twI2[m*48 + a];
            const float2 u  = uv[m*49 + c];
            acc += 2.0f*(tw.x*u.x - tw.y*u.y);
        }
        dst[o] = acc*(1.0f/2304.0f);
    }
}

extern "C" void kernel_launch(void* const* d_in, const int* in_sizes, int n_in,
                              void* d_out, int out_size, void* d_ws, size_t ws_size,
                              hipStream_t stream){
    (void)in_sizes; (void)n_in; (void)out_size;
    const float* x    = (const float*)d_in[0];   // (16,16,48,48,48) f32
    const float* kern = (const float*)d_in[1];   // (16,16,12) f32
    float* out = (float*)d_out;

    char* ws = (char*)d_ws;
    size_t o = 0;
    auto nb = [&](size_t bytes){ size_t r = o; o += (bytes + 255) & ~(size_t)255; return r; };
    float*  wig_w = (float*) (ws + nb(884352ull*4));
    float*  wig_u = (float*) (ws + nb(884352ull*4));
    float2* conjD = (float2*)(ws + nb(221088ull*8));
    float2* tw1a  = (float2*)(ws + nb(1152ull*8));
    float2* tw1b  = (float2*)(ws + nb(2304ull*8));
    float2* twI1  = (float2*)(ws + nb(2256ull*8));
    float2* twI2  = (float2*)(ws + nb(1152ull*8));
    float2* big0  = (float2*)(ws + nb(14155776ull*8)); // A1, later S
    float2* big1  = (float2*)(ws + nb(14155776ull*8)); // Xf, later U
    float2* Fx    = (float2*)(ws + nb(4716544ull*8));
    float2* Fy    = (float2*)(ws + nb(4716544ull*8));
    float2* Fz    = (float2*)(ws + nb(4716544ull*8));
    if (o > ws_size) return; // insufficient workspace -> fail loudly in validation

    k0_wigner <<<dim3(24,60),  dim3(64),  0, stream>>>(wig_w, wig_u, conjD);
    k_twiddles<<<dim3(1),      dim3(256), 0, stream>>>(tw1a, tw1b, twI1, twI2);
    k1a       <<<dim3(48,256), dim3(192), 0, stream>>>(x, tw1a, big0);
    k1b       <<<dim3(24,48,2),dim3(256), 0, stream>>>(big0, tw1b, big1);
    k2        <<<dim3(47,47),  dim3(256), 0, stream>>>(big1, wig_w, Fx);
    k3        <<<dim3(NSPEC),  dim3(256), 0, stream>>>(kern, conjD, Fy);
    k4        <<<dim3(NSPEC),  dim3(64),  0, stream>>>(Fx, Fy, Fz);
    k5        <<<dim3(24,47),  dim3(256), 0, stream>>>(Fz, wig_u, big0);
    i1        <<<dim3(24,48,2),dim3(256), 0, stream>>>(big0, twI1, big1);
    i2        <<<dim3(256,48), dim3(256), 0, stream>>>(big1, twI2, out);
}

// Round 2
// 1822.825 us; speedup vs baseline: 1.3706x; 1.3706x over previous
//
#include <hip/hip_runtime.h>
#include <math.h>

#define NSPEC 18424

static constexpr int OFF[25] = {0,1,10,35,84,165,286,455,680,969,1330,1771,2300,2925,
                                3654,4495,5456,6545,7770,9139,10660,12341,14190,16215,18424};
// per-l 64x64 tile counts: CT(l) = l/2+1; BACC = prefix of CT^2
static constexpr int BACC[25] = {0,1,2,6,10,19,28,44,60,85,110,146,182,231,280,344,
                                 408,489,570,670,770,891,1012,1156,1300};
static constexpr double PI_D = 3.14159265358979323846264338327950288;
static constexpr float SCALING_F = 0.07216878364870322f; // 1/sqrt(12*16)

__device__ __forceinline__ void cfma(float2& acc, float2 a, float2 b){
    acc.x += a.x*b.x - a.y*b.y;
    acc.y += a.x*b.y + a.y*b.x;
}

// ---------------------------------------------------------------------------
// K0: Wigner-d tables on device (fp64). grid (l=24, beta=60), block 256.
// Flattened (r,c) element loop: full lane use, ~5x better critical path at l=23.
// ---------------------------------------------------------------------------
__global__ __launch_bounds__(256) void k0_wigner(float* __restrict__ wig_w,
                                                 float* __restrict__ wig_u,
                                                 float2* __restrict__ conjD){
    const int l = blockIdx.x, bi = blockIdx.y, L = 2*l+1;
    __shared__ double lnf[104];
    const int t = threadIdx.x;
    for (int i = t; i < 104; i += 256){
        double s = 0.0;
        for (int k = 2; k <= i; ++k) s += log((double)k);
        lnf[i] = s;
    }
    __syncthreads();
    double beta, alpha = 0.0, wq = 0.0;
    const bool isq = (bi < 48);
    if (isq){
        beta = (bi + 0.5)*PI_D/48.0;
        double acc = 0.0;
        for (int k = 0; k < 24; ++k)
            acc += sin((double)(2*bi+1)*(double)(2*k+1)*PI_D/96.0)/(double)(2*k+1);
        wq = (2.0/24.0)*sin(PI_D*(double)(2*bi+1)/96.0)*acc*0.5;
    } else {
        int p = bi - 48;
        alpha = (double)(p >> 1)*(PI_D/3.0);
        beta  = (p & 1) ? PI_D/8.0 : PI_D/16.0;
    }
    const double ch = cos(0.5*beta), sh = sin(0.5*beta);
    const double lc = log(ch), ls = log(sh);
    for (int e = t; e < L*L; e += 256){
        const int r = e / L, c = e % L;
        const int mp = r - l, mm = c - l;
        const int k0 = max(0, mm - mp), k1 = min(l + mm, l - mp);
        const double pre = 0.5*(lnf[l+mp] + lnf[l-mp] + lnf[l+mm] + lnf[l-mm]);
        double d = 0.0;
        for (int k = k0; k <= k1; ++k){
            const int ec = 2*l - 2*k + mm - mp, es = 2*k + mp - mm;
            const double term = exp(pre - lnf[l+mm-k] - lnf[k] - lnf[mp-mm+k]
                                    - lnf[l-mp-k] + (double)ec*lc + (double)es*ls);
            d += ((mp - mm + k) & 1) ? -term : term;
        }
        if (isq){
            const int idx = 48*OFF[l] + (bi*L + r)*L + c;
            wig_w[idx] = (float)(wq*d);
            wig_u[idx] = (float)((double)(2*l+1)*d);
        } else {
            const int p = bi - 48;
            conjD[(size_t)p*NSPEC + OFF[l] + r*L + c] =
                make_float2((float)(cos((double)mp*alpha)*d),
                            (float)(sin((double)mp*alpha)*d));
        }
    }
}

// K0b: twiddle tables (fp64 -> fp32). 1 block, 256 threads.
__global__ __launch_bounds__(256) void k_twiddles(float2* __restrict__ tw1a,
                                                  float2* __restrict__ tw1b,
                                                  float2* __restrict__ twI1,
                                                  float2* __restrict__ twI2){
    const int t = threadIdx.x;
    for (int i = t; i < 24*48; i += 256){
        int m = i/48, a = i%48;
        double th = 2.0*PI_D*(double)(m*a)/48.0;
        tw1a[i] = make_float2((float)cos(th), (float)(-sin(th)));
        twI2[i] = make_float2((float)cos(th), (float)sin(th));
    }
    for (int i = t; i < 48*48; i += 256){
        int n = i/48, c = i%48;
        double th = 2.0*PI_D*(double)(n*c)/48.0;
        tw1b[i] = make_float2((float)cos(th), (float)(-sin(th)));
    }
    for (int i = t; i < 47*48; i += 256){
        int nn = i/48, c = i%48;
        double th = 2.0*PI_D*(double)((nn-23)*c)/48.0;
        twI1[i] = make_float2((float)cos(th), (float)sin(th));
    }
}

// ---------------------------------------------------------------------------
// K1a: DFT over axis a (real->cmplx), m = 0..23 (Hermitian half). Twiddles in LDS.
// ---------------------------------------------------------------------------
__global__ __launch_bounds__(192) void k1a(const float* __restrict__ x,
                                           const float2* __restrict__ tw1a,
                                           float2* __restrict__ A1){
    const int j = blockIdx.x, z = blockIdx.y;
    __shared__ float xs[48*49];
    __shared__ float2 tws[24*48];
    for (int e = threadIdx.x; e < 1152; e += 192) tws[e] = tw1a[e];
    const float* src = x + (size_t)(z*48 + j)*2304;
    for (int e = threadIdx.x; e < 2304; e += 192)
        xs[(e/48)*49 + (e%48)] = src[e];
    __syncthreads();
    const int c = threadIdx.x % 48, mq = threadIdx.x / 48;
    float ar[6], ai[6];
    #pragma unroll
    for (int i = 0; i < 6; ++i){ ar[i] = 0.f; ai[i] = 0.f; }
    for (int a = 0; a < 48; ++a){
        const float xv = xs[a*49 + c];
        #pragma unroll
        for (int i = 0; i < 6; ++i){
            const float2 tw = tws[(mq*6 + i)*48 + a];
            ar[i] += xv*tw.x; ai[i] += xv*tw.y;
        }
    }
    #pragma unroll
    for (int i = 0; i < 6; ++i){
        const int m = mq*6 + i;
        A1[((size_t)(j*24 + m)*256 + z)*48 + c] = make_float2(ar[i], ai[i]);
    }
}

// ---------------------------------------------------------------------------
// K1b: DFT over axis c. Twiddles in LDS.
// ---------------------------------------------------------------------------
__global__ __launch_bounds__(256) void k1b(const float2* __restrict__ A1,
                                           const float2* __restrict__ tw1b,
                                           float2* __restrict__ Xf){
    const int m = blockIdx.x, j = blockIdx.y, zt = blockIdx.z;
    __shared__ float2 as_[48*129];
    __shared__ float2 tws[48*48];
    for (int e = threadIdx.x; e < 2304; e += 256) tws[e] = tw1b[e];
    const float2* src = A1 + ((size_t)(j*24 + m)*256 + zt*128)*48;
    for (int e = threadIdx.x; e < 6144; e += 256)
        as_[(e%48)*129 + (e/48)] = src[e];
    __syncthreads();
    const int z = threadIdx.x & 127, nh = threadIdx.x >> 7;
    float2 acc[24];
    #pragma unroll
    for (int i = 0; i < 24; ++i) acc[i] = make_float2(0.f, 0.f);
    for (int cc = 0; cc < 48; ++cc){
        const float2 xv = as_[cc*129 + z];
        #pragma unroll
        for (int i = 0; i < 24; ++i)
            cfma(acc[i], xv, tws[(nh*24 + i)*48 + cc]);
    }
    #pragma unroll
    for (int i = 0; i < 24; ++i){
        const int n = nh*24 + i;
        Xf[((size_t)(j*24 + m)*48 + n)*256 + zt*128 + z] = acc[i];
    }
}

// ---------------------------------------------------------------------------
// K2: Wigner beta-quadrature -> Fx[s][z]. (unchanged)
// ---------------------------------------------------------------------------
__global__ __launch_bounds__(256) void k2(const float2* __restrict__ Xf,
                                          const float* __restrict__ wigw,
                                          float2* __restrict__ Fx){
    const int mf = (int)blockIdx.x - 23, nf = (int)blockIdx.y - 23;
    const int z = threadIdx.x;
    const int am = mf < 0 ? -mf : mf;
    const int anf = nf < 0 ? -nf : nf;
    const int lmin = am > anf ? am : anf;
    const int nidx = ((mf < 0 ? -nf : nf) + 48) % 48;
    const float sgn = mf < 0 ? -1.f : 1.f;
    float ar[24], ai[24];
    int widx[24];
    #pragma unroll
    for (int l = 0; l < 24; ++l){
        ar[l] = 0.f; ai[l] = 0.f;
        widx[l] = 48*OFF[l] + (l+mf)*(2*l+1) + (l+nf);
    }
    for (int j = 0; j < 48; ++j){
        const float2 xv = Xf[((size_t)(j*24 + am)*48 + nidx)*256 + z];
        const float xi = sgn*xv.y;
        #pragma unroll
        for (int l = 0; l < 24; ++l){
            if (l >= lmin){
                const float w = wigw[widx[l]];
                ar[l] += w*xv.x; ai[l] += w*xi;
            }
            widx[l] += (2*l+1)*(2*l+1);
        }
    }
    #pragma unroll
    for (int l = 0; l < 24; ++l){
        if (l >= lmin){
            const int L = 2*l+1;
            Fx[((size_t)(OFF[l] + (l+mf)*L + (l+nf)))*256 + z] = make_float2(ar[l], ai[l]);
        }
    }
}

// K3: Fy[s][f*16+g] = SCALING * sum_p kern[f,g,p] * conjD[p][s]  (unchanged)
__global__ __launch_bounds__(256) void k3(const float* __restrict__ kern,
                                          const float2* __restrict__ conjD,
                                          float2* __restrict__ Fy){
    const int s = blockIdx.x, t = threadIdx.x;
    float kr[12];
    #pragma unroll
    for (int p = 0; p < 12; ++p) kr[p] = kern[t*12 + p];
    float accr = 0.f, acci = 0.f;
    #pragma unroll
    for (int p = 0; p < 12; ++p){
        const float2 D = conjD[(size_t)p*NSPEC + s];
        accr += kr[p]*D.x; acci += kr[p]*D.y;
    }
    Fy[(size_t)s*256 + t] = make_float2(SCALING_F*accr, SCALING_F*acci);
}

// ---------------------------------------------------------------------------
// K4: so3_mm as per-l complex GEMM, 64x64 tile, 256 thr, 4x4 complex/thread.
// Zbig[(mr,b),(nc,g)] = sum_k sum_f Xbig[(mr,b),(k,f)] * Ybig[(k,f),(nc,g)]
// ---------------------------------------------------------------------------
__global__ __launch_bounds__(256) void k4g(const float2* __restrict__ Fx,
                                           const float2* __restrict__ Fy,
                                           float2* __restrict__ Fz){
    const int bid = blockIdx.x;
    int l = 0;
    #pragma unroll
    for (int i = 1; i < 24; ++i) if (bid >= BACC[i]) l = i;
    const int L = 2*l+1, CT = l/2 + 1;
    const int tb = bid - BACC[l];
    const int bm = tb / CT, bn = tb % CT;
    const int t = threadIdx.x;
    const int lane = t & 63, seg = t >> 6;
    const int tr = t >> 4, tc = t & 15;
    __shared__ float2 As[16*64];   // [f][r]
    __shared__ float2 Bs[16*64];   // [f][c]
    float2 acc[4][4];
    #pragma unroll
    for (int i = 0; i < 4; ++i)
        #pragma unroll
        for (int jj = 0; jj < 4; ++jj) acc[i][jj] = make_float2(0.f, 0.f);

    const int mr = bm*4 + seg;
    const int nc = bn*4 + seg;
    const bool va = (mr < L), vb = (nc < L);
    const float2* aPtr = Fx + (size_t)(OFF[l] + (va ? mr : 0)*L)*256 + lane*4;
    const float2* bPtr = Fy + (size_t)(OFF[l] + (vb ? nc : 0))*256 + lane*4;
    // LDS write coords
    const int bA  = lane >> 2;            // b (A row within 16-group)
    const int fA0 = (lane & 3)*4;         // f base for A elements
    const int fB  = lane >> 2;            // f for B
    const int gB0 = (lane & 3)*4;         // g base for B

    for (int k = 0; k < L; ++k){
        float2 a0={0,0},a1={0,0},a2={0,0},a3={0,0};
        float2 b0={0,0},b1={0,0},b2={0,0},b3={0,0};
        if (va){ const float2* p = aPtr + (size_t)k*256; a0=p[0]; a1=p[1]; a2=p[2]; a3=p[3]; }
        if (vb){ const float2* p = bPtr + (size_t)k*L*256; b0=p[0]; b1=p[1]; b2=p[2]; b3=p[3]; }
        __syncthreads();   // previous iteration's reads complete
        As[(fA0+0)*64 + seg*16 + bA] = a0;
        As[(fA0+1)*64 + seg*16 + bA] = a1;
        As[(fA0+2)*64 + seg*16 + bA] = a2;
        As[(fA0+3)*64 + seg*16 + bA] = a3;
        Bs[fB*64 + seg*16 + gB0 + 0] = b0;
        Bs[fB*64 + seg*16 + gB0 + 1] = b1;
        Bs[fB*64 + seg*16 + gB0 + 2] = b2;
        Bs[fB*64 + seg*16 + gB0 + 3] = b3;
        __syncthreads();
        #pragma unroll
        for (int f = 0; f < 16; ++f){
            float2 av0 = As[f*64 + tr*4 + 0];
            float2 av1 = As[f*64 + tr*4 + 1];
            float2 av2 = As[f*64 + tr*4 + 2];
            float2 av3 = As[f*64 + tr*4 + 3];
            float2 bv0 = Bs[f*64 + tc*4 + 0];
            float2 bv1 = Bs[f*64 + tc*4 + 1];
            float2 bv2 = Bs[f*64 + tc*4 + 2];
            float2 bv3 = Bs[f*64 + tc*4 + 3];
            cfma(acc[0][0], av0, bv0); cfma(acc[0][1], av0, bv1);
            cfma(acc[0][2], av0, bv2); cfma(acc[0][3], av0, bv3);
            cfma(acc[1][0], av1, bv0); cfma(acc[1][1], av1, bv1);
            cfma(acc[1][2], av1, bv2); cfma(acc[1][3], av1, bv3);
            cfma(acc[2][0], av2, bv0); cfma(acc[2][1], av2, bv1);
            cfma(acc[2][2], av2, bv2); cfma(acc[2][3], av2, bv3);
            cfma(acc[3][0], av3, bv0); cfma(acc[3][1], av3, bv1);
            cfma(acc[3][2], av3, bv2); cfma(acc[3][3], av3, bv3);
        }
    }
    #pragma unroll
    for (int i = 0; i < 4; ++i){
        const int r = tr*4 + i;
        const int mro = bm*4 + (r >> 4), b = r & 15;
        if (mro < L){
            #pragma unroll
            for (int jj = 0; jj < 4; ++jj){
                const int c = tc*4 + jj;
                const int nco = bn*4 + (c >> 4), g = c & 15;
                if (nco < L)
                    Fz[((size_t)(OFF[l] + mro*L + nco))*256 + b*16 + g] = acc[i][jj];
            }
        }
    }
}

// ---------------------------------------------------------------------------
// K5: inverse Wigner -> S[m][nn][j][z] (unchanged)
// ---------------------------------------------------------------------------
__global__ __launch_bounds__(256) void k5(const float2* __restrict__ Fz,
                                          const float* __restrict__ wigu,
                                          float2* __restrict__ S){
    const int mf = blockIdx.x;            // 0..23
    const int nf = (int)blockIdx.y - 23;  // -23..23
    const int z = threadIdx.x;
    const int anf = nf < 0 ? -nf : nf;
    const int lmin = mf > anf ? mf : anf;
    float2 fz[24];
    int widx[24];
    #pragma unroll
    for (int l = 0; l < 24; ++l){
        const int L = 2*l+1;
        fz[l] = (l >= lmin) ? Fz[((size_t)(OFF[l] + (l+mf)*L + (l+nf)))*256 + z]
                            : make_float2(0.f, 0.f);
        widx[l] = 48*OFF[l] + (l+mf)*L + (l+nf);
    }
    const int nn = nf + 23;
    for (int j = 0; j < 48; ++j){
        float sr = 0.f, si = 0.f;
        #pragma unroll
        for (int l = 0; l < 24; ++l){
            if (l >= lmin){
                const float w = wigu[widx[l]];
                sr += w*fz[l].x; si += w*fz[l].y;
            }
            widx[l] += (2*l+1)*(2*l+1);
        }
        S[((size_t)(mf*47 + nn)*48 + j)*256 + z] = make_float2(sr, si);
    }
}

// ---------------------------------------------------------------------------
// I1: inverse DFT over n. Twiddles in LDS; stores transposed via LDS so global
// writes are 384B-contiguous runs. U layout [j][z][m][c].
// ---------------------------------------------------------------------------
__global__ __launch_bounds__(256) void i1(const float2* __restrict__ S,
                                          const float2* __restrict__ twI1,
                                          float2* __restrict__ U){
    const int m = blockIdx.x, j = blockIdx.y, zt = blockIdx.z;
    __shared__ float2 sbuf[128*49];     // compute: [nn][z] (47x128); then [z][c] pad49
    __shared__ float2 tws[47*48];
    for (int e = threadIdx.x; e < 2256; e += 256) tws[e] = twI1[e];
    for (int e = threadIdx.x; e < 47*128; e += 256){
        const int nn = e >> 7, zl = e & 127;
        sbuf[nn*128 + zl] = S[((size_t)(m*47 + nn)*48 + j)*256 + zt*128 + zl];
    }
    __syncthreads();
    const int z = threadIdx.x & 127, ch = threadIdx.x >> 7;
    float2 acc[24];
    #pragma unroll
    for (int i = 0; i < 24; ++i) acc[i] = make_float2(0.f, 0.f);
    for (int nn = 0; nn < 47; ++nn){
        const float2 sv = sbuf[nn*128 + z];
        #pragma unroll
        for (int i = 0; i < 24; ++i)
            cfma(acc[i], sv, tws[nn*48 + ch*24 + i]);
    }
    __syncthreads();
    #pragma unroll
    for (int i = 0; i < 24; ++i)
        sbuf[z*49 + ch*24 + i] = acc[i];
    __syncthreads();
    float2* dst = U + (size_t)(j*256 + zt*128)*1152 + m*48;
    for (int e = threadIdx.x; e < 6144; e += 256){
        const int zz = e/48, c = e%48;
        dst[(size_t)zz*1152 + c] = sbuf[zz*49 + c];
    }
}

// ---------------------------------------------------------------------------
// I2: inverse DFT over m with Hermitian combine -> real out. Twiddles in LDS.
// ---------------------------------------------------------------------------
__global__ __launch_bounds__(256) void i2(const float2* __restrict__ U,
                                          const float2* __restrict__ twI2,
                                          float* __restrict__ out){
    const int z = blockIdx.x, j = blockIdx.y;
    __shared__ float2 uv[24*49];
    __shared__ float2 tws[24*48];
    for (int e = threadIdx.x; e < 1152; e += 256) tws[e] = twI2[e];
    const float2* src = U + (size_t)(j*256 + z)*1152;
    for (int e = threadIdx.x; e < 1152; e += 256)
        uv[(e/48)*49 + (e%48)] = src[e];
    __syncthreads();
    float* dst = out + (size_t)(z*48 + j)*2304;
    for (int o = threadIdx.x; o < 2304; o += 256){
        const int a = o / 48, c = o % 48;
        float acc = uv[c].x;  // m = 0 term
        #pragma unroll
        for (int m = 1; m < 24; ++m){
            const float2 tw = tws[m*48 + a];
            const float2 u  = uv[m*49 + c];
            acc += 2.0f*(tw.x*u.x - tw.y*u.y);
        }
        dst[o] = acc*(1.0f/2304.0f);
    }
}

extern "C" void kernel_launch(void* const* d_in, const int* in_sizes, int n_in,
                              void* d_out, int out_size, void* d_ws, size_t ws_size,
                              hipStream_t stream){
    (void)in_sizes; (void)n_in; (void)out_size;
    const float* x    = (const float*)d_in[0];   // (16,16,48,48,48) f32
    const float* kern = (const float*)d_in[1];   // (16,16,12) f32
    float* out = (float*)d_out;

    char* ws = (char*)d_ws;
    size_t o = 0;
    auto nb = [&](size_t bytes){ size_t r = o; o += (bytes + 255) & ~(size_t)255; return r; };
    float*  wig_w = (float*) (ws + nb(884352ull*4));
    float*  wig_u = (float*) (ws + nb(884352ull*4));
    float2* conjD = (float2*)(ws + nb(221088ull*8));
    float2* tw1a  = (float2*)(ws + nb(1152ull*8));
    float2* tw1b  = (float2*)(ws + nb(2304ull*8));
    float2* twI1  = (float2*)(ws + nb(2256ull*8));
    float2* twI2  = (float2*)(ws + nb(1152ull*8));
    float2* big0  = (float2*)(ws + nb(14155776ull*8)); // A1, later S
    float2* big1  = (float2*)(ws + nb(14155776ull*8)); // Xf, later U
    float2* Fx    = (float2*)(ws + nb(4716544ull*8));
    float2* Fy    = (float2*)(ws + nb(4716544ull*8));
    float2* Fz    = (float2*)(ws + nb(4716544ull*8));
    if (o > ws_size) return;

    k0_wigner <<<dim3(24,60),  dim3(256), 0, stream>>>(wig_w, wig_u, conjD);
    k_twiddles<<<dim3(1),      dim3(256), 0, stream>>>(tw1a, tw1b, twI1, twI2);
    k1a       <<<dim3(48,256), dim3(192), 0, stream>>>(x, tw1a, big0);
    k1b       <<<dim3(24,48,2),dim3(256), 0, stream>>>(big0, tw1b, big1);
    k2        <<<dim3(47,47),  dim3(256), 0, stream>>>(big1, wig_w, Fx);
    k3        <<<dim3(NSPEC),  dim3(256), 0, stream>>>(kern, conjD, Fy);
    k4g       <<<dim3(1300),   dim3(256), 0, stream>>>(Fx, Fy, Fz);
    k5        <<<dim3(24,47),  dim3(256), 0, stream>>>(Fz, wig_u, big0);
    i1        <<<dim3(24,48,2),dim3(256), 0, stream>>>(big0, twI1, big1);
    i2        <<<dim3(256,48), dim3(256), 0, stream>>>(big1, twI2, out);
}

// Round 3
// 1586.405 us; speedup vs baseline: 1.5748x; 1.1490x over previous
//
#include <hip/hip_runtime.h>
#include <math.h>

#define NSPEC 18424

static constexpr int OFF[25] = {0,1,10,35,84,165,286,455,680,969,1330,1771,2300,2925,
                                3654,4495,5456,6545,7770,9139,10660,12341,14190,16215,18424};
// k4 tiles: heavy-l first. sizes (l=23..0): RT(l)*CT(l), RT=ceil((l+1)/4), CT=l/2+1
static constexpr int P24[25] = {0,72,144,210,276,326,376,421,466,498,530,558,586,604,622,
                                637,652,660,668,674,680,682,684,685,686};
static constexpr double PI_D = 3.14159265358979323846264338327950288;
static constexpr float SCALING_F = 0.07216878364870322f; // 1/sqrt(12*16)

__device__ __forceinline__ void cfma(float2& acc, float2 a, float2 b){
    acc.x += a.x*b.x - a.y*b.y;
    acc.y += a.x*b.y + a.y*b.x;
}

// ---------------------------------------------------------------------------
// K_tables: twiddles + lnf prefix (one small block, runs before k0).
// ---------------------------------------------------------------------------
__global__ __launch_bounds__(256) void k_tables(float2* __restrict__ tw1a,
                                                float2* __restrict__ tw1b,
                                                float2* __restrict__ twI1,
                                                float2* __restrict__ twI2,
                                                double* __restrict__ lnfg){
    const int t = threadIdx.x;
    __shared__ double lt[104];
    if (t < 104) lt[t] = (t >= 2) ? log((double)t) : 0.0;
    __syncthreads();
    if (t == 0){
        double run = 0.0;
        for (int i = 0; i < 104; ++i){ run += lt[i]; lnfg[i] = run; }
    }
    for (int i = t; i < 24*48; i += 256){
        int m = i/48, a = i%48;
        double th = 2.0*PI_D*(double)(m*a)/48.0;
        tw1a[i] = make_float2((float)cos(th), (float)(-sin(th)));
        twI2[i] = make_float2((float)cos(th), (float)sin(th));
    }
    for (int i = t; i < 48*48; i += 256){
        int n = i/48, c = i%48;
        double th = 2.0*PI_D*(double)(n*c)/48.0;
        tw1b[i] = make_float2((float)cos(th), (float)(-sin(th)));
    }
    for (int i = t; i < 47*48; i += 256){
        int nn = i/48, c = i%48;
        double th = 2.0*PI_D*(double)((nn-23)*c)/48.0;
        twI1[i] = make_float2((float)cos(th), (float)sin(th));
    }
}

// ---------------------------------------------------------------------------
// K0: Wigner-d tables (fp64). grid (l=24, beta=60), block 256.
// lnf from global; per-element term recurrence: 1 exp per element.
// ---------------------------------------------------------------------------
__global__ __launch_bounds__(256) void k0_wigner(const double* __restrict__ lnfg,
                                                 float* __restrict__ wig_w,
                                                 float* __restrict__ wig_u,
                                                 float2* __restrict__ conjD){
    const int l = blockIdx.x, bi = blockIdx.y, L = 2*l+1;
    __shared__ double lnf[104];
    __shared__ double rcpt[105];
    const int t = threadIdx.x;
    for (int i = t; i < 104; i += 256) lnf[i] = lnfg[i];
    for (int i = t; i < 105; i += 256) rcpt[i] = (i > 0) ? 1.0/(double)i : 0.0;
    __syncthreads();
    double beta, alpha = 0.0, wq = 0.0;
    const bool isq = (bi < 48);
    if (isq){
        beta = (bi + 0.5)*PI_D/48.0;
        double acc = 0.0;
        for (int k = 0; k < 24; ++k)
            acc += sin((double)(2*bi+1)*(double)(2*k+1)*PI_D/96.0)/(double)(2*k+1);
        wq = (2.0/24.0)*sin(PI_D*(double)(2*bi+1)/96.0)*acc*0.5;
    } else {
        int p = bi - 48;
        alpha = (double)(p >> 1)*(PI_D/3.0);
        beta  = (p & 1) ? PI_D/8.0 : PI_D/16.0;
    }
    const double ch = cos(0.5*beta), sh = sin(0.5*beta);
    const double lc = log(ch), ls = log(sh);
    const double t2 = (sh/ch)*(sh/ch);
    for (int e = t; e < L*L; e += 256){
        const int r = e / L, c = e % L;
        const int mp = r - l, mm = c - l;
        const int k0 = max(0, mm - mp), k1 = min(l + mm, l - mp);
        double d = 0.0;
        if (k1 >= k0){
            const double pre = 0.5*(lnf[l+mp] + lnf[l-mp] + lnf[l+mm] + lnf[l-mm]);
            const int ec = 2*l - 2*k0 + mm - mp, es = 2*k0 + mp - mm;
            double term = exp(pre - lnf[l+mm-k0] - lnf[k0] - lnf[mp-mm+k0] - lnf[l-mp-k0]
                              + (double)ec*lc + (double)es*ls);
            double sgn = ((mp - mm + k0) & 1) ? -1.0 : 1.0;
            double n1 = (double)(l + mm - k0);
            double n2 = (double)(l - mp - k0);
            d = sgn*term;
            for (int k = k0; k < k1; ++k){
                term *= n1 * n2 * rcpt[k+1] * rcpt[mp-mm+k+1] * t2;
                n1 -= 1.0; n2 -= 1.0;
                sgn = -sgn;
                d += sgn*term;
            }
        }
        if (isq){
            const int idx = 48*OFF[l] + (bi*L + r)*L + c;
            wig_w[idx] = (float)(wq*d);
            wig_u[idx] = (float)((double)(2*l+1)*d);
        } else {
            const int p = bi - 48;
            conjD[(size_t)p*NSPEC + OFF[l] + r*L + c] =
                make_float2((float)(cos((double)mp*alpha)*d),
                            (float)(sin((double)mp*alpha)*d));
        }
    }
}

// ---------------------------------------------------------------------------
// K1a: DFT over axis a (real->cmplx), m = 0..23 (Hermitian half).
// ---------------------------------------------------------------------------
__global__ __launch_bounds__(192) void k1a(const float* __restrict__ x,
                                           const float2* __restrict__ tw1a,
                                           float2* __restrict__ A1){
    const int j = blockIdx.x, z = blockIdx.y;
    __shared__ float xs[48*49];
    __shared__ float2 tws[24*48];
    for (int e = threadIdx.x; e < 1152; e += 192) tws[e] = tw1a[e];
    const float* src = x + (size_t)(z*48 + j)*2304;
    for (int e = threadIdx.x; e < 2304; e += 192)
        xs[(e/48)*49 + (e%48)] = src[e];
    __syncthreads();
    const int c = threadIdx.x % 48, mq = threadIdx.x / 48;
    float ar[6], ai[6];
    #pragma unroll
    for (int i = 0; i < 6; ++i){ ar[i] = 0.f; ai[i] = 0.f; }
    for (int a = 0; a < 48; ++a){
        const float xv = xs[a*49 + c];
        #pragma unroll
        for (int i = 0; i < 6; ++i){
            const float2 tw = tws[(mq*6 + i)*48 + a];
            ar[i] += xv*tw.x; ai[i] += xv*tw.y;
        }
    }
    #pragma unroll
    for (int i = 0; i < 6; ++i){
        const int m = mq*6 + i;
        A1[((size_t)(j*24 + m)*256 + z)*48 + c] = make_float2(ar[i], ai[i]);
    }
}

// ---------------------------------------------------------------------------
// K1b: DFT over axis c. Twiddles via wave-uniform global (scalar) loads.
// ---------------------------------------------------------------------------
__global__ __launch_bounds__(256) void k1b(const float2* __restrict__ A1,
                                           const float2* __restrict__ tw1b,
                                           float2* __restrict__ Xf){
    const int m = blockIdx.x, j = blockIdx.y, zt = blockIdx.z;
    __shared__ float2 as_[48*129];
    const float2* src = A1 + ((size_t)(j*24 + m)*256 + zt*128)*48;
    for (int e = threadIdx.x; e < 6144; e += 256)
        as_[(e%48)*129 + (e/48)] = src[e];
    __syncthreads();
    const int z = threadIdx.x & 127, nh = threadIdx.x >> 7;
    float2 acc[24];
    #pragma unroll
    for (int i = 0; i < 24; ++i) acc[i] = make_float2(0.f, 0.f);
    for (int cc = 0; cc < 48; ++cc){
        const float2 xv = as_[cc*129 + z];
        #pragma unroll
        for (int i = 0; i < 24; ++i)
            cfma(acc[i], xv, tw1b[(nh*24 + i)*48 + cc]);
    }
    #pragma unroll
    for (int i = 0; i < 24; ++i){
        const int n = nh*24 + i;
        Xf[((size_t)(j*24 + m)*48 + n)*256 + zt*128 + z] = acc[i];
    }
}

// ---------------------------------------------------------------------------
// K2: Wigner beta-quadrature -> Fx[s][z], only mf >= 0 rows (k4 reads only those).
// ---------------------------------------------------------------------------
__global__ __launch_bounds__(256) void k2(const float2* __restrict__ Xf,
                                          const float* __restrict__ wigw,
                                          float2* __restrict__ Fx){
    const int mf = blockIdx.x;                 // 0..23
    const int nf = (int)blockIdx.y - 23;       // -23..23
    const int z = threadIdx.x;
    const int anf = nf < 0 ? -nf : nf;
    const int lmin = mf > anf ? mf : anf;
    const int nidx = (nf + 48) % 48;
    float ar[24], ai[24];
    int widx[24];
    #pragma unroll
    for (int l = 0; l < 24; ++l){
        ar[l] = 0.f; ai[l] = 0.f;
        widx[l] = 48*OFF[l] + (l+mf)*(2*l+1) + (l+nf);
    }
    for (int j = 0; j < 48; ++j){
        const float2 xv = Xf[((size_t)(j*24 + mf)*48 + nidx)*256 + z];
        #pragma unroll
        for (int l = 0; l < 24; ++l){
            if (l >= lmin){
                const float w = wigw[widx[l]];
                ar[l] += w*xv.x; ai[l] += w*xv.y;
            }
            widx[l] += (2*l+1)*(2*l+1);
        }
    }
    #pragma unroll
    for (int l = 0; l < 24; ++l){
        if (l >= lmin){
            const int L = 2*l+1;
            Fx[((size_t)(OFF[l] + (l+mf)*L + (l+nf)))*256 + z] = make_float2(ar[l], ai[l]);
        }
    }
}

// K3: Fy[s][f*16+g] = SCALING * sum_p kern[f,g,p] * conjD[p][s]
__global__ __launch_bounds__(256) void k3(const float* __restrict__ kern,
                                          const float2* __restrict__ conjD,
                                          float2* __restrict__ Fy){
    const int s = blockIdx.x, t = threadIdx.x;
    float kr[12];
    #pragma unroll
    for (int p = 0; p < 12; ++p) kr[p] = kern[t*12 + p];
    float accr = 0.f, acci = 0.f;
    #pragma unroll
    for (int p = 0; p < 12; ++p){
        const float2 D = conjD[(size_t)p*NSPEC + s];
        accr += kr[p]*D.x; acci += kr[p]*D.y;
    }
    Fy[(size_t)s*256 + t] = make_float2(SCALING_F*accr, SCALING_F*acci);
}

// ---------------------------------------------------------------------------
// K4: per-l complex GEMM, only output rows mr >= l (all k5 ever reads).
// 64x64 tile, 256 thr; thread owns rows tr+16i, cols tc+16j (conflict-free LDS).
// ---------------------------------------------------------------------------
__global__ __launch_bounds__(256) void k4g(const float2* __restrict__ Fx,
                                           const float2* __restrict__ Fy,
                                           float2* __restrict__ Fz){
    const int bid = blockIdx.x;
    int idx = 0;
    #pragma unroll
    for (int i = 1; i < 24; ++i) if (bid >= P24[i]) idx = i;
    const int l = 23 - idx;
    const int L = 2*l+1, CT = l/2 + 1;
    const int tb = bid - P24[idx];
    const int bm = tb / CT, bn = tb % CT;

    const int t = threadIdx.x;
    const int lane = t & 63, w = t >> 6;
    const int tc = t & 15, tr = t >> 4;

    __shared__ float2 As[16*64];   // [f][row]
    __shared__ float2 Bs[16*64];   // [f][col]

    float2 acc[4][4];
    #pragma unroll
    for (int i = 0; i < 4; ++i)
        #pragma unroll
        for (int jj = 0; jj < 4; ++jj) acc[i][jj] = make_float2(0.f, 0.f);

    const int mrA = l + bm*4 + w;              // A source row (absolute mr)
    const int ncB = bn*4 + w;                  // B source col
    const bool aok = (bm*4 + w <= l);
    const bool bok = (ncB < L);
    const float2* aBase = Fx + (size_t)(OFF[l] + mrA*L)*256 + lane*4;
    const float2* bBase = Fy + (size_t)(OFF[l] + ncB)*256 + lane*4;

    // LDS staging coords
    const int fA = (lane & 3)*4;               // A: f base
    const int rA = w*16 + (lane >> 2);         // A: tile row
    const int fB = lane >> 2;                  // B: f
    const int cB = w*16 + (lane & 3)*4;        // B: col base

    float2 ra0={0,0}, ra1={0,0}, ra2={0,0}, ra3={0,0};
    float2 rb0={0,0}, rb1={0,0}, rb2={0,0}, rb3={0,0};
    if (aok){ const float2* p = aBase; ra0=p[0]; ra1=p[1]; ra2=p[2]; ra3=p[3]; }
    if (bok){ const float2* p = bBase; rb0=p[0]; rb1=p[1]; rb2=p[2]; rb3=p[3]; }

    for (int k = 0; k < L; ++k){
        __syncthreads();
        As[(fA+0)*64 + rA] = ra0;
        As[(fA+1)*64 + rA] = ra1;
        As[(fA+2)*64 + rA] = ra2;
        As[(fA+3)*64 + rA] = ra3;
        {
            float4* bp = (float4*)&Bs[fB*64 + cB];
            bp[0] = make_float4(rb0.x, rb0.y, rb1.x, rb1.y);
            bp[1] = make_float4(rb2.x, rb2.y, rb3.x, rb3.y);
        }
        __syncthreads();
        if (k + 1 < L){
            if (aok){ const float2* p = aBase + (size_t)(k+1)*256; ra0=p[0]; ra1=p[1]; ra2=p[2]; ra3=p[3]; }
            if (bok){ const float2* p = bBase + (size_t)(k+1)*L*256; rb0=p[0]; rb1=p[1]; rb2=p[2]; rb3=p[3]; }
        }
        #pragma unroll
        for (int f = 0; f < 16; ++f){
            const float2 av0 = As[f*64 + tr];
            const float2 av1 = As[f*64 + tr + 16];
            const float2 av2 = As[f*64 + tr + 32];
            const float2 av3 = As[f*64 + tr + 48];
            const float2 bv0 = Bs[f*64 + tc];
            const float2 bv1 = Bs[f*64 + tc + 16];
            const float2 bv2 = Bs[f*64 + tc + 32];
            const float2 bv3 = Bs[f*64 + tc + 48];
            cfma(acc[0][0], av0, bv0); cfma(acc[0][1], av0, bv1);
            cfma(acc[0][2], av0, bv2); cfma(acc[0][3], av0, bv3);
            cfma(acc[1][0], av1, bv0); cfma(acc[1][1], av1, bv1);
            cfma(acc[1][2], av1, bv2); cfma(acc[1][3], av1, bv3);
            cfma(acc[2][0], av2, bv0); cfma(acc[2][1], av2, bv1);
            cfma(acc[2][2], av2, bv2); cfma(acc[2][3], av2, bv3);
            cfma(acc[3][0], av3, bv0); cfma(acc[3][1], av3, bv1);
            cfma(acc[3][2], av3, bv2); cfma(acc[3][3], av3, bv3);
        }
    }
    #pragma unroll
    for (int i = 0; i < 4; ++i){
        if (bm*4 + i <= l){
            const int mro = l + bm*4 + i;
            #pragma unroll
            for (int jj = 0; jj < 4; ++jj){
                const int nco = bn*4 + jj;
                if (nco < L)
                    Fz[((size_t)(OFF[l] + mro*L + nco))*256 + t] = acc[i][jj];
            }
        }
    }
}

// ---------------------------------------------------------------------------
// K5: inverse Wigner -> S[m][nn][j][z] (m = 0..23 Hermitian half)
// ---------------------------------------------------------------------------
__global__ __launch_bounds__(256) void k5(const float2* __restrict__ Fz,
                                          const float* __restrict__ wigu,
                                          float2* __restrict__ S){
    const int mf = blockIdx.x;            // 0..23
    const int nf = (int)blockIdx.y - 23;  // -23..23
    const int z = threadIdx.x;
    const int anf = nf < 0 ? -nf : nf;
    const int lmin = mf > anf ? mf : anf;
    float2 fz[24];
    int widx[24];
    #pragma unroll
    for (int l = 0; l < 24; ++l){
        const int L = 2*l+1;
        fz[l] = (l >= lmin) ? Fz[((size_t)(OFF[l] + (l+mf)*L + (l+nf)))*256 + z]
                            : make_float2(0.f, 0.f);
        widx[l] = 48*OFF[l] + (l+mf)*L + (l+nf);
    }
    const int nn = nf + 23;
    for (int j = 0; j < 48; ++j){
        float sr = 0.f, si = 0.f;
        #pragma unroll
        for (int l = 0; l < 24; ++l){
            if (l >= lmin){
                const float w = wigu[widx[l]];
                sr += w*fz[l].x; si += w*fz[l].y;
            }
            widx[l] += (2*l+1)*(2*l+1);
        }
        S[((size_t)(mf*47 + nn)*48 + j)*256 + z] = make_float2(sr, si);
    }
}

// ---------------------------------------------------------------------------
// I1: inverse DFT over n; twiddles via wave-uniform global loads; transposed
// store through LDS. U layout [j][z][m][c].
// ---------------------------------------------------------------------------
__global__ __launch_bounds__(256) void i1(const float2* __restrict__ S,
                                          const float2* __restrict__ twI1,
                                          float2* __restrict__ U){
    const int m = blockIdx.x, j = blockIdx.y, zt = blockIdx.z;
    __shared__ float2 sbuf[128*49];
    for (int e = threadIdx.x; e < 47*128; e += 256){
        const int nn = e >> 7, zl = e & 127;
        sbuf[nn*128 + zl] = S[((size_t)(m*47 + nn)*48 + j)*256 + zt*128 + zl];
    }
    __syncthreads();
    const int z = threadIdx.x & 127, ch = threadIdx.x >> 7;
    float2 acc[24];
    #pragma unroll
    for (int i = 0; i < 24; ++i) acc[i] = make_float2(0.f, 0.f);
    for (int nn = 0; nn < 47; ++nn){
        const float2 sv = sbuf[nn*128 + z];
        #pragma unroll
        for (int i = 0; i < 24; ++i)
            cfma(acc[i], sv, twI1[nn*48 + ch*24 + i]);
    }
    __syncthreads();
    #pragma unroll
    for (int i = 0; i < 24; ++i)
        sbuf[z*49 + ch*24 + i] = acc[i];
    __syncthreads();
    float2* dst = U + (size_t)(j*256 + zt*128)*1152 + m*48;
    for (int e = threadIdx.x; e < 6144; e += 256){
        const int zz = e/48, c = e%48;
        dst[(size_t)zz*1152 + c] = sbuf[zz*49 + c];
    }
}

// ---------------------------------------------------------------------------
// I2: inverse DFT over m with Hermitian combine -> real out.
// ---------------------------------------------------------------------------
__global__ __launch_bounds__(256) void i2(const float2* __restrict__ U,
                                          const float2* __restrict__ twI2,
                                          float* __restrict__ out){
    const int z = blockIdx.x, j = blockIdx.y;
    __shared__ float2 uv[24*49];
    __shared__ float2 tws[24*48];
    for (int e = threadIdx.x; e < 1152; e += 256) tws[e] = twI2[e];
    const float2* src = U + (size_t)(j*256 + z)*1152;
    for (int e = threadIdx.x; e < 1152; e += 256)
        uv[(e/48)*49 + (e%48)] = src[e];
    __syncthreads();
    float* dst = out + (size_t)(z*48 + j)*2304;
    for (int o = threadIdx.x; o < 2304; o += 256){
        const int a = o / 48, c = o % 48;
        float acc = uv[c].x;  // m = 0 term
        #pragma unroll
        for (int m = 1; m < 24; ++m){
            const float2 tw = tws[m*48 + a];
            const float2 u  = uv[m*49 + c];
            acc += 2.0f*(tw.x*u.x - tw.y*u.y);
        }
        dst[o] = acc*(1.0f/2304.0f);
    }
}

extern "C" void kernel_launch(void* const* d_in, const int* in_sizes, int n_in,
                              void* d_out, int out_size, void* d_ws, size_t ws_size,
                              hipStream_t stream){
    (void)in_sizes; (void)n_in; (void)out_size;
    const float* x    = (const float*)d_in[0];   // (16,16,48,48,48) f32
    const float* kern = (const float*)d_in[1];   // (16,16,12) f32
    float* out = (float*)d_out;

    char* ws = (char*)d_ws;
    size_t o = 0;
    auto nb = [&](size_t bytes){ size_t r = o; o += (bytes + 255) & ~(size_t)255; return r; };
    float*  wig_w = (float*) (ws + nb(884352ull*4));
    float*  wig_u = (float*) (ws + nb(884352ull*4));
    float2* conjD = (float2*)(ws + nb(221088ull*8));
    float2* tw1a  = (float2*)(ws + nb(1152ull*8));
    float2* tw1b  = (float2*)(ws + nb(2304ull*8));
    float2* twI1  = (float2*)(ws + nb(2256ull*8));
    float2* twI2  = (float2*)(ws + nb(1152ull*8));
    double* lnfg  = (double*)(ws + nb(104ull*8));
    float2* big0  = (float2*)(ws + nb(14155776ull*8)); // A1, later S
    float2* big1  = (float2*)(ws + nb(14155776ull*8)); // Xf, later U
    float2* Fx    = (float2*)(ws + nb(4716544ull*8));
    float2* Fy    = (float2*)(ws + nb(4716544ull*8));
    float2* Fz    = (float2*)(ws + nb(4716544ull*8));
    if (o > ws_size) return;

    k_tables  <<<dim3(1),      dim3(256), 0, stream>>>(tw1a, tw1b, twI1, twI2, lnfg);
    k0_wigner <<<dim3(24,60),  dim3(256), 0, stream>>>(lnfg, wig_w, wig_u, conjD);
    k1a       <<<dim3(48,256), dim3(192), 0, stream>>>(x, tw1a, big0);
    k1b       <<<dim3(24,48,2),dim3(256), 0, stream>>>(big0, tw1b, big1);
    k2        <<<dim3(24,47),  dim3(256), 0, stream>>>(big1, wig_w, Fx);
    k3        <<<dim3(NSPEC),  dim3(256), 0, stream>>>(kern, conjD, Fy);
    k4g       <<<dim3(686),    dim3(256), 0, stream>>>(Fx, Fy, Fz);
    k5        <<<dim3(24,47),  dim3(256), 0, stream>>>(Fz, wig_u, big0);
    i1        <<<dim3(24,48,2),dim3(256), 0, stream>>>(big0, twI1, big1);
    i2        <<<dim3(256,48), dim3(256), 0, stream>>>(big1, twI2, out);
}